// Round 16
// baseline (952.593 us; speedup 1.0000x reference)
//
#include <hip/hip_runtime.h>
#include <hip/hip_bf16.h>
#include <stdint.h>

typedef __hip_bfloat16 bf16;
typedef float f32x4 __attribute__((ext_vector_type(4)));
typedef short s16x8 __attribute__((ext_vector_type(8)));
typedef short s16x4 __attribute__((ext_vector_type(4)));

#define DEV __device__ __forceinline__

static constexpr int S_ = 2048, H_ = 1024, D_ = 512, I_ = 4096, V_ = 32000;
static constexpr int SLn = 32, Lc = 2;
static constexpr size_t LOGITS_N = (size_t)S_ * V_;

DEV float gelu_f(float x) {
    float x3 = x * x * x;
    return 0.5f * x * (1.f + tanhf(0.7978845608028654f * (x + 0.044715f * x3)));
}

#define AS1(p) ((const __attribute__((address_space(1))) void*)(uintptr_t)(p))
#define AS3(p) ((__attribute__((address_space(3))) void*)(uint32_t)(uintptr_t)(p))

// ============ logits GEMM: 256x256, BK=32, issue-early pipelined ============
// R16: identical to R10/R15 except setprio removed from MM — m190 evidence:
// setprio hurts barrier-locked lockstep GEMM (T5 needs wave role-split,
// absent here).
__global__ __launch_bounds__(512, 1) void logits_gemm(const bf16* __restrict__ A,
                                                      const bf16* __restrict__ BT,
                                                      float* __restrict__ C) {
    constexpr int NT = 32;
    __shared__ short lds[4 * 16384];
    const int tid = threadIdx.x, lane = tid & 63;
    const int wid = tid >> 6;
    const int wm = wid >> 2, wn = wid & 3;

    int bid = blockIdx.x;
    int wgid = (bid & 7) * 125 + (bid >> 3);
    const int m0 = (wgid & 7) * 256;
    const int n0 = (wgid >> 3) * 256;

    const int L = tid * 16;
    const int sidx = L >> 10, w = L & 1023;
    const int r16 = w >> 6;
    const int c2 = (w & 63) ^ (((r16 >> 3) & 1) << 5);
    const int srow = sidx * 16 + r16;
    const int scol = c2 >> 1;
    const bf16* aSrc[2];
    const bf16* bSrc[2];
#pragma unroll
    for (int h = 0; h < 2; ++h) {
        aSrc[h] = A + (size_t)(m0 + h * 128 + srow) * 1536 + scol;
        bSrc[h] = BT + (size_t)(n0 + h * 128 + srow) * 1024 + scol;
    }
    auto STA = [&](int kt, int h) {
        __builtin_amdgcn_global_load_lds(AS1(aSrc[h] + kt * 32),
                                         AS3(&lds[(kt & 3) * 16384 + h * 4096 + tid * 8]), 16, 0, 0);
    };
    auto STB = [&](int kt, int h) {
        __builtin_amdgcn_global_load_lds(AS1(bSrc[h] + kt * 32),
                                         AS3(&lds[(kt & 3) * 16384 + 8192 + h * 4096 + tid * 8]), 16, 0, 0);
    };

    const int laneoff = (lane & 15) * 32 + (((lane >> 4) * 8) ^ (((lane >> 3) & 1) << 4));

    f32x4 acc[8][4];
#pragma unroll
    for (int i = 0; i < 8; i++)
#pragma unroll
        for (int j = 0; j < 4; j++)
#pragma unroll
            for (int r = 0; r < 4; r++) acc[i][j][r] = 0.f;

    s16x8 a0[4], a1[4], b0[4], b1[4];
    auto rdA = [&](s16x8(&d)[4], int kt, int mq) {
        const short* p = &lds[(kt & 3) * 16384 + wm * 4096 + mq * 2048];
#pragma unroll
        for (int f = 0; f < 4; ++f) d[f] = *(const s16x8*)&p[f * 512 + laneoff];
    };
    auto rdB = [&](s16x8(&d)[4], int kt) {
        const short* p = &lds[(kt & 3) * 16384 + 8192 + wn * 2048];
#pragma unroll
        for (int j = 0; j < 4; ++j) d[j] = *(const s16x8*)&p[j * 512 + laneoff];
    };
    auto MM = [&](int mq, s16x8(&a)[4], s16x8(&b)[4]) {
#pragma unroll
        for (int f = 0; f < 4; ++f)
#pragma unroll
            for (int j = 0; j < 4; ++j)
                acc[mq * 4 + f][j] =
                    __builtin_amdgcn_mfma_f32_16x16x32_bf16(a[f], b[j], acc[mq * 4 + f][j], 0, 0, 0);
    };

#define GATE(tight)                                                     \
    do {                                                                \
        __builtin_amdgcn_s_barrier();                                   \
        if (tight) asm volatile("s_waitcnt vmcnt(0)" ::: "memory");     \
        else       asm volatile("s_waitcnt vmcnt(4)" ::: "memory");     \
        asm volatile("s_waitcnt lgkmcnt(0)" ::: "memory");              \
        __builtin_amdgcn_sched_barrier(0);                              \
    } while (0)
#define SB() __builtin_amdgcn_sched_barrier(0)

#pragma unroll
    for (int kt = 0; kt < 3; ++kt) {
        STA(kt, 0); STA(kt, 1); STB(kt, 0); STB(kt, 1);
    }
    asm volatile("s_waitcnt vmcnt(4)" ::: "memory");
    __builtin_amdgcn_s_barrier();
    rdA(a0, 0, 0);
    rdB(b0, 0);

    for (int tt = 0; tt < NT; tt += 2) {
        {
            const int t = tt;
            const bool tight = (t >= NT - 2);
            GATE(tight);
            rdA(a1, t, 1);
            SB();
            MM(0, a0, b0);
            if (t + 3 < NT) { STA(t + 3, 0); STA(t + 3, 1); }
            GATE(tight);
            if (t + 1 < NT) { rdA(a0, t + 1, 0); rdB(b1, t + 1); }
            SB();
            MM(1, a1, b0);
            if (t + 3 < NT) { STB(t + 3, 0); STB(t + 3, 1); }
        }
        {
            const int t = tt + 1;
            const bool tight = (t >= NT - 2);
            GATE(tight);
            rdA(a1, t, 1);
            SB();
            MM(0, a0, b1);
            if (t + 3 < NT) { STA(t + 3, 0); STA(t + 3, 1); }
            GATE(tight);
            if (t + 1 < NT) { rdA(a0, t + 1, 0); rdB(b0, t + 1); }
            SB();
            MM(1, a1, b1);
            if (t + 3 < NT) { STB(t + 3, 0); STB(t + 3, 1); }
        }
    }
#undef GATE
#undef SB

#pragma unroll
    for (int i = 0; i < 8; i++) {
        int gr0 = m0 + wm * 128 + i * 16 + ((lane >> 4) << 2);
#pragma unroll
        for (int j = 0; j < 4; j++) {
            int gc = n0 + wn * 64 + j * 16 + (lane & 15);
#pragma unroll
            for (int r = 0; r < 4; r++) C[(size_t)(gr0 + r) * V_ + gc] = acc[i][j][r];
        }
    }
}

// ======================= unified pipelined GEMM (NT) ========================
// BK=32, 4 LDS slots, 3-ahead prefetch, R8-fixed vmcnt ladder (passed 6x).
// FLAGS: 1=bias, 2=gelu, 4=f32, 8=bf16, 32=IQ-route
template <int BM, int BN, int TH, int WM, int WN, int FLAGS>
__global__ __launch_bounds__(TH, 3) void gemm_p5(
    const bf16* __restrict__ A, int lda, const bf16* __restrict__ BT,
    const float* __restrict__ bias, const float* __restrict__ bias2,
    float* __restrict__ Cf, int ldf, bf16* __restrict__ Cb, int ldb2,
    bf16* __restrict__ Cb2, int K, int Mt, int Nt) {
    constexpr int FM = BM / (WM * 16), FN = BN / (WN * 16);
    constexpr int CA = (BM * 4) / TH, CB = (BN * 4) / TH, CH = CA + CB;
    constexpr int NPH = (FM * FN >= 32) ? 2 : 1;
    constexpr int FMP = FM / NPH;
    constexpr int BUFS = (BM + BN) * 32;
    __shared__ short lds[4 * BUFS];
    const int tid = threadIdx.x, lane = tid & 63;
    const int wm = (tid >> 6) / WN, wn = (tid >> 6) % WN;

    int nwg = Mt * Nt;
    int bid = blockIdx.x, wgid = bid;
    if ((nwg & 7) == 0) {
        int cpx = nwg >> 3;
        wgid = (bid & 7) * cpx + (bid >> 3);
    }
    const int m0 = (wgid % Mt) * BM, n0 = (wgid / Mt) * BN;

    const bf16* aS[CA];
    const bf16* bS[CB];
#pragma unroll
    for (int c = 0; c < CA; ++c) {
        int L = (c * TH + tid) * 16;
        int sidx = L >> 10, w = L & 1023;
        int r16 = w >> 6;
        int c2 = (w & 63) ^ (((r16 >> 3) & 1) << 5);
        aS[c] = A + (size_t)(m0 + sidx * 16 + r16) * lda + (c2 >> 1);
    }
#pragma unroll
    for (int c = 0; c < CB; ++c) {
        int L = (c * TH + tid) * 16;
        int sidx = L >> 10, w = L & 1023;
        int r16 = w >> 6;
        int c2 = (w & 63) ^ (((r16 >> 3) & 1) << 5);
        bS[c] = BT + (size_t)(n0 + sidx * 16 + r16) * K + (c2 >> 1);
    }

    auto stageA = [&](int kt) {
        short* dst = &lds[(kt & 3) * BUFS];
#pragma unroll
        for (int c = 0; c < CA; ++c)
            __builtin_amdgcn_global_load_lds(AS1(aS[c] + kt * 32), AS3(dst + (c * TH + tid) * 8), 16, 0, 0);
    };
    auto stageB = [&](int kt) {
        short* dst = &lds[(kt & 3) * BUFS + BM * 32];
#pragma unroll
        for (int c = 0; c < CB; ++c)
            __builtin_amdgcn_global_load_lds(AS1(bS[c] + kt * 32), AS3(dst + (c * TH + tid) * 8), 16, 0, 0);
    };

    const int laneoff = ((lane & 15) * 64 + ((((lane >> 4) * 8) ^ (((lane >> 3) & 1) << 4)) << 1)) >> 1;

    f32x4 acc[FM][FN];
#pragma unroll
    for (int i = 0; i < FM; i++)
#pragma unroll
        for (int j = 0; j < FN; j++)
#pragma unroll
            for (int r = 0; r < 4; r++) acc[i][j][r] = 0.f;

    const int NT = K >> 5;
    stageA(0); stageB(0);
    stageA(1); stageB(1);
    stageA(2); stageB(2);
    asm volatile("s_waitcnt vmcnt(%0)" ::"n"(2 * CH) : "memory");
    __builtin_amdgcn_s_barrier();
    for (int t = 0; t < NT; ++t) {
        const short* as = &lds[(t & 3) * BUFS];
        const short* bs = as + BM * 32;
        s16x8 bf[FN];
#pragma unroll
        for (int p = 0; p < NPH; ++p) {
            s16x8 af[FMP];
#pragma unroll
            for (int i = 0; i < FMP; i++)
                af[i] = *(const s16x8*)&as[(wm * FM + p * FMP + i) * 512 + laneoff];
            if (p == 0) {
#pragma unroll
                for (int j = 0; j < FN; j++)
                    bf[j] = *(const s16x8*)&bs[(wn * FN + j) * 512 + laneoff];
            }
            if (t + 3 < NT) {
                if (NPH == 1) {
                    stageA(t + 3);
                    stageB(t + 3);
                } else if (p == 0) {
                    stageA(t + 3);
                } else {
                    stageB(t + 3);
                }
            }
            if (p == NPH - 1) {
                const int rem = NT - 1 - t;
                if (rem >= 3)
                    asm volatile("s_waitcnt vmcnt(%0)" ::"n"(2 * CH) : "memory");
                else if (rem == 2)
                    asm volatile("s_waitcnt vmcnt(%0)" ::"n"(CH) : "memory");
                else
                    asm volatile("s_waitcnt vmcnt(0)" ::: "memory");
            }
            __builtin_amdgcn_s_barrier();
            __builtin_amdgcn_sched_barrier(0);
            __builtin_amdgcn_s_setprio(1);
#pragma unroll
            for (int i = 0; i < FMP; i++)
#pragma unroll
                for (int j = 0; j < FN; j++)
                    acc[p * FMP + i][j] =
                        __builtin_amdgcn_mfma_f32_16x16x32_bf16(af[i], bf[j], acc[p * FMP + i][j], 0, 0, 0);
            __builtin_amdgcn_s_setprio(0);
            __builtin_amdgcn_s_barrier();
        }
    }

#pragma unroll
    for (int i = 0; i < FM; i++) {
        int gr0 = m0 + (wm * FM + i) * 16 + ((lane >> 4) << 2);
#pragma unroll
        for (int j = 0; j < FN; j++) {
            int gc = n0 + (wn * FN + j) * 16 + (lane & 15);
            if (FLAGS & 32) {
                if (gc < 512) {
                    float bv = bias[gc];
#pragma unroll
                    for (int r = 0; r < 4; r++) {
                        float v = acc[i][j][r] + bv;
                        Cf[(size_t)(gr0 + r) * 512 + gc] = v;
                        Cb2[(size_t)(gr0 + r) * 512 + gc] = __float2bfloat16(v);
                    }
                } else {
                    float bv = bias2[gc - 512];
#pragma unroll
                    for (int r = 0; r < 4; r++)
                        Cb[(size_t)(gr0 + r) * 1536 + (gc - 512)] = __float2bfloat16(acc[i][j][r] + bv);
                }
            } else {
                float bv = (FLAGS & 1) ? bias[gc] : 0.f;
#pragma unroll
                for (int r = 0; r < 4; r++) {
                    float v = acc[i][j][r] + bv;
                    if (FLAGS & 2) v = gelu_f(v);
                    if (FLAGS & 4) Cf[(size_t)(gr0 + r) * ldf + gc] = v;
                    if (FLAGS & 8) Cb[(size_t)(gr0 + r) * ldb2 + gc] = __float2bfloat16(v);
                }
            }
        }
    }
}

// ------------------------ transpose f32 -> bf16^T ---------------------------
__global__ __launch_bounds__(256) void transpose_bf16_kernel(const float* __restrict__ W,
                                                             bf16* __restrict__ WT, int K, int N) {
    __shared__ float t[32][33];
    int tx = threadIdx.x & 31, ty = threadIdx.x >> 5;
    int kb = blockIdx.y * 32, nb = blockIdx.x * 32;
#pragma unroll
    for (int i = 0; i < 4; i++)
        t[ty + 8 * i][tx] = W[(size_t)(kb + ty + 8 * i) * N + nb + tx];
    __syncthreads();
#pragma unroll
    for (int i = 0; i < 4; i++)
        WT[(size_t)(nb + ty + 8 * i) * K + kb + tx] = __float2bfloat16(t[tx][ty + 8 * i]);
}

// ------------------------------ f32 -> bf16 ---------------------------------
__global__ void conv_bf16_kernel(const float* __restrict__ src, bf16* __restrict__ dst) {
    size_t i = (size_t)blockIdx.x * 256 + threadIdx.x;
    f32x4 v = ((const f32x4*)src)[i];
    s16x4 o;
#pragma unroll
    for (int j = 0; j < 4; j++) {
        bf16 h = __float2bfloat16(v[j]);
        o[j] = *(short*)&h;
    }
    ((s16x4*)dst)[i] = o;
}

// ------------------------------ embedding ----------------------------------
__global__ void embed_kernel(const int* __restrict__ ids, const float* __restrict__ emb,
                             const float* __restrict__ pos, float* __restrict__ hF,
                             bf16* __restrict__ hB) {
    int t = blockIdx.x, tid = threadIdx.x;
    int id = ids[t];
    f32x4 v = ((const f32x4*)(emb + (size_t)id * H_))[tid];
    f32x4 q = ((const f32x4*)(pos + (size_t)t * H_))[tid];
    v = v + q;
    ((f32x4*)(hF + (size_t)t * H_))[tid] = v;
    s16x4 o;
#pragma unroll
    for (int j = 0; j < 4; j++) {
        bf16 h = __float2bfloat16(v[j]);
        o[j] = *(short*)&h;
    }
    ((s16x4*)(hB + (size_t)t * 1536))[tid] = o;
}

// ------------------------------ LayerNorm ----------------------------------
__global__ __launch_bounds__(256) void ln_kernel(const float* __restrict__ x,
                                                 const float* __restrict__ res,
                                                 const float* __restrict__ g,
                                                 const float* __restrict__ b,
                                                 float* __restrict__ of, bf16* __restrict__ ob,
                                                 int ldo) {
    __shared__ float red[8];
    int row = blockIdx.x, tid = threadIdx.x, lane = tid & 63, wid = tid >> 6;
    const float* xr = x + (size_t)row * H_;
    float v[4];
#pragma unroll
    for (int j = 0; j < 4; j++) {
        int c = tid + 256 * j;
        v[j] = xr[c] + (res ? res[(size_t)row * H_ + c] : 0.f);
    }
    float s = v[0] + v[1] + v[2] + v[3];
#pragma unroll
    for (int o = 32; o; o >>= 1) s += __shfl_xor(s, o);
    if (!lane) red[wid] = s;
    __syncthreads();
    float mean = (red[0] + red[1] + red[2] + red[3]) * (1.f / H_);
    float q = 0.f;
#pragma unroll
    for (int j = 0; j < 4; j++) {
        float d = v[j] - mean;
        q += d * d;
    }
#pragma unroll
    for (int o = 32; o; o >>= 1) q += __shfl_xor(q, o);
    if (!lane) red[4 + wid] = q;
    __syncthreads();
    float var = (red[4] + red[5] + red[6] + red[7]) * (1.f / H_);
    float rstd = rsqrtf(var + 1e-5f);
#pragma unroll
    for (int j = 0; j < 4; j++) {
        int c = tid + 256 * j;
        float o2 = (v[j] - mean) * rstd * g[c] + b[c];
        if (of) of[(size_t)row * H_ + c] = o2;
        if (ob) ob[(size_t)row * ldo + c] = __float2bfloat16(o2);
    }
}

// --------------------- mem transpose for attn scores ------------------------
__global__ void memt_kernel(const float* __restrict__ fast0, const float* __restrict__ slow0,
                            float* __restrict__ memT) {
    int idx = blockIdx.x * 256 + threadIdx.x;
    int d = idx >> 6, n = idx & 63;
    const float* m = (n < 32) ? fast0 + (size_t)n * D_ : slow0 + (size_t)(n - 32) * D_;
    memT[idx] = m[d];
}

// ---------------- attention (fused keynorm), 1 q-row per wave ---------------
__global__ __launch_bounds__(256) void attn_kernel(const float* __restrict__ keys,
                                                   const float* __restrict__ memT,
                                                   const float* __restrict__ fast0,
                                                   const float* __restrict__ slow0,
                                                   bf16* __restrict__ qr, bf16* __restrict__ hr) {
    __shared__ float klds[4][512];
    int wid = threadIdx.x >> 6, lane = threadIdx.x & 63;
    int r = blockIdx.x * 4 + wid;
    float kv[8], ss = 0.f;
#pragma unroll
    for (int j = 0; j < 8; j++) {
        kv[j] = keys[(size_t)r * D_ + lane + 64 * j];
        ss += kv[j] * kv[j];
    }
#pragma unroll
    for (int o = 32; o; o >>= 1) ss += __shfl_xor(ss, o);
    float inv = 1.f / (sqrtf(ss) + 1e-6f);
#pragma unroll
    for (int j = 0; j < 8; j++) {
        kv[j] *= inv;
        klds[wid][lane + 64 * j] = kv[j];
    }
    __syncthreads();
    float s0 = 0.f, s1 = 0.f, s2 = 0.f, s3 = 0.f;
#pragma unroll 8
    for (int d = 0; d < 512; d += 4) {
        s0 = fmaf(klds[wid][d + 0], memT[(d + 0) * 64 + lane], s0);
        s1 = fmaf(klds[wid][d + 1], memT[(d + 1) * 64 + lane], s1);
        s2 = fmaf(klds[wid][d + 2], memT[(d + 2) * 64 + lane], s2);
        s3 = fmaf(klds[wid][d + 3], memT[(d + 3) * 64 + lane], s3);
    }
    float s = (s0 + s1 + s2 + s3) * 0.044194173824159216f;
    float m = s;
#pragma unroll
    for (int o = 32; o; o >>= 1) m = fmaxf(m, __shfl_xor(m, o));
    float p = expf(s - m);
    float sum = p;
#pragma unroll
    for (int o = 32; o; o >>= 1) sum += __shfl_xor(sum, o);
    float pn = p / sum;
    float rv[8];
#pragma unroll
    for (int j = 0; j < 8; j++) rv[j] = 0.f;
    for (int n2 = 0; n2 < 64; ++n2) {
        float a2 = __shfl(pn, n2);
        const float* m2 = (n2 < 32) ? (fast0 + (size_t)n2 * D_) : (slow0 + (size_t)(n2 - 32) * D_);
#pragma unroll
        for (int j = 0; j < 8; j++) rv[j] = fmaf(a2, m2[lane + 64 * j], rv[j]);
    }
#pragma unroll
    for (int j = 0; j < 8; j++) {
        bf16 o = __float2bfloat16(rv[j] * kv[j]);
        qr[(size_t)r * 1536 + 1024 + lane + 64 * j] = o;
        hr[(size_t)r * 1536 + 1024 + lane + 64 * j] = o;
    }
}

// ------------------------- scan coefficients --------------------------------
__global__ void coef_kernel(float* __restrict__ coef) {
    int t = blockIdx.x * 256 + threadIdx.x;
    int j0 = (t + 9) / 10;
    float a = powf(0.9f, (float)(2047 - t + 205 - j0));
    float b = 0.f;
    for (int j = j0; j < 205; ++j)
        b += powf(0.9f, (float)(10 * j - t + j - j0)) * powf(0.99f, (float)(204 - j));
    b *= 0.1f;
    coef[t] = a;
    coef[2048 + t] = b;
    if (t == 0) {
        coef[4096] = powf(0.99f, 205.f);
        float cfs = 0.f;
        for (int j = 0; j < 205; ++j)
            cfs += powf(0.9f, (float)(11 * j + 1)) * powf(0.99f, (float)(204 - j));
        coef[4097] = 0.1f * cfs;
    }
}

// -------------------- gates epilogue: sigmoid * coef ------------------------
__global__ void sigcoef_kernel(const float* __restrict__ raw, const float* __restrict__ coef,
                               float* __restrict__ ga, float* __restrict__ gb) {
    int i = blockIdx.x * 256 + threadIdx.x;
    int r = i >> 5, n = i & 31;
    float g = 1.f / (1.f + expf(-raw[r * 64 + n]));
    ga[i] = g * coef[r];
    gb[i] = g * coef[2048 + r];
}

// ------------------------- scan: split-T partial GEMMs ----------------------
__global__ __launch_bounds__(256) void scan_part_kernel(const float* __restrict__ items,
                                                        const float* __restrict__ ga,
                                                        const float* __restrict__ gb,
                                                        float* __restrict__ pF,
                                                        float* __restrict__ pS) {
    int tid = threadIdx.x;
    int d = (blockIdx.x & 7) * 64 + (tid & 63);
    int mg = (blockIdx.x >> 3) & 1;
    int tc = blockIdx.x >> 4;
    int m0 = mg * 16 + (tid >> 6) * 4;
    float aF[4] = {0.f, 0.f, 0.f, 0.f}, aS[4] = {0.f, 0.f, 0.f, 0.f};
    for (int t = tc * 128; t < tc * 128 + 128; ++t) {
        float it = items[(size_t)t * D_ + d];
#pragma unroll
        for (int j = 0; j < 4; j++) {
            aF[j] = fmaf(ga[t * 32 + m0 + j], it, aF[j]);
            aS[j] = fmaf(gb[t * 32 + m0 + j], it, aS[j]);
        }
    }
#pragma unroll
    for (int j = 0; j < 4; j++) {
        pF[((size_t)tc * 32 + m0 + j) * D_ + d] = aF[j];
        pS[((size_t)tc * 32 + m0 + j) * D_ + d] = aS[j];
    }
}

__global__ __launch_bounds__(256) void scan_reduce_kernel(const float* __restrict__ pF,
                                                          const float* __restrict__ pS,
                                                          const float* __restrict__ coef,
                                                          const float* __restrict__ fast0,
                                                          const float* __restrict__ slow0,
                                                          float* __restrict__ fastO,
                                                          float* __restrict__ slowO) {
    int i = blockIdx.x * 256 + threadIdx.x;
    float f = 0.f, s = 0.f;
#pragma unroll
    for (int c = 0; c < 16; c++) {
        f += pF[(size_t)c * 32 * D_ + i];
        s += pS[(size_t)c * 32 * D_ + i];
    }
    fastO[i] = f;
    slowO[i] = s + coef[4096] * slow0[i] + coef[4097] * fast0[i];
}

// ------------------------------- host side ----------------------------------
static inline void gemmM(hipStream_t st, const bf16* A, int lda, const bf16* BT,
                         const float* bias, const float* bias2, float* Cf, int ldf, bf16* Cb,
                         int ldb2, bf16* Cb2, int M, int N, int K, int flags) {
    if (N >= 1536 && (N % 128) == 0) {
        int Mt = M / 128, Nt = N / 128;
        dim3 g(Mt * Nt), b(256);
        if (flags == 33)
            gemm_p5<128, 128, 256, 2, 2, 33><<<g, b, 0, st>>>(A, lda, BT, bias, bias2, Cf, ldf,
                                                              Cb, ldb2, Cb2, K, Mt, Nt);
        else if (flags == 11)
            gemm_p5<128, 128, 256, 2, 2, 11><<<g, b, 0, st>>>(A, lda, BT, bias, bias2, Cf, ldf,
                                                              Cb, ldb2, Cb2, K, Mt, Nt);
        else
            gemm_p5<128, 128, 256, 2, 2, 5><<<g, b, 0, st>>>(A, lda, BT, bias, bias2, Cf, ldf,
                                                             Cb, ldb2, Cb2, K, Mt, Nt);
        return;
    }
    int Mt = M / 128, Nt = N / 64;
    dim3 g(Mt * Nt), b(256);
    if (flags == 11)
        gemm_p5<128, 64, 256, 2, 2, 11><<<g, b, 0, st>>>(A, lda, BT, bias, bias2, Cf, ldf, Cb,
                                                         ldb2, Cb2, K, Mt, Nt);
    else
        gemm_p5<128, 64, 256, 2, 2, 5><<<g, b, 0, st>>>(A, lda, BT, bias, bias2, Cf, ldf, Cb,
                                                        ldb2, Cb2, K, Mt, Nt);
}

static inline void transp(hipStream_t st, const float* W, bf16* WT, int K, int N) {
    transpose_bf16_kernel<<<dim3(N / 32, K / 32), 256, 0, st>>>(W, WT, K, N);
}

extern "C" void kernel_launch(void* const* d_in, const int* in_sizes, int n_in,
                              void* d_out, int out_size, void* d_ws, size_t ws_size,
                              hipStream_t stream) {
    const int* ids = (const int*)d_in[0];
    const float* fastS = (const float*)d_in[1];
    const float* slowS = (const float*)d_in[2];
    const float* emb = (const float*)d_in[3];
    const float* pos = (const float*)d_in[4];
    const float* W_item = (const float*)d_in[5];
    const float* b_item = (const float*)d_in[6];
    const float* W_q = (const float*)d_in[7];
    const float* b_q = (const float*)d_in[8];
    const float* rh_W1 = (const float*)d_in[9];
    const float* rh_b1 = (const float*)d_in[10];
    const float* rh_W2 = (const float*)d_in[11];
    const float* rh_b2 = (const float*)d_in[12];
    const float* gate_W = (const float*)d_in[13];
    const float* gate_b = (const float*)d_in[14];
    const float* W_out = (const float*)d_in[15];
    const float* b_out = (const float*)d_in[16];
    const float* ln1_g = (const float*)d_in[17];
    const float* ln1_b = (const float*)d_in[18];
    const float* ffn_W1 = (const float*)d_in[19];
    const float* ffn_b1 = (const float*)d_in[20];
    const float* ffn_W2 = (const float*)d_in[21];
    const float* ffn_b2 = (const float*)d_in[22];
    const float* ln2_g = (const float*)d_in[23];
    const float* ln2_b = (const float*)d_in[24];
    const float* fln_g = (const float*)d_in[25];
    const float* fln_b = (const float*)d_in[26];
    float* outP = (float*)d_out;

    size_t off = 0;
    char* base = (char*)d_ws;
    auto alloc = [&](size_t n) -> char* {
        char* p = base + off;
        off += (n + 255) & ~(size_t)255;
        return p;
    };
    bf16* wIQ = (bf16*)alloc((size_t)Lc * 1536 * H_ * 2);
    bf16* rh1T = (bf16*)alloc((size_t)Lc * (2 * D_) * D_ * 2);
    bf16* rh2T = (bf16*)alloc((size_t)Lc * D_ * (2 * D_) * 2);
    bf16* wOutT = (bf16*)alloc((size_t)Lc * H_ * 1536 * 2);
    bf16* f1T = (bf16*)alloc((size_t)Lc * I_ * H_ * 2);
    bf16* f2T = (bf16*)alloc((size_t)Lc * H_ * I_ * 2);
    bf16* gWT = (bf16*)alloc((size_t)Lc * 64 * 1536 * 2);
    bf16* embB = (bf16*)alloc((size_t)V_ * H_ * 2);
    float* hF = (float*)alloc((size_t)S_ * H_ * 4);
    bf16* hrB = (bf16*)alloc((size_t)S_ * 1536 * 2);
    bf16* hB = hrB;
    float* itemsF = (float*)alloc((size_t)S_ * D_ * 4);
    bf16* itemsB = (bf16*)alloc((size_t)S_ * D_ * 2);
    bf16* qrB = (bf16*)alloc((size_t)S_ * 1536 * 2);
    bf16* k1B = (bf16*)alloc((size_t)S_ * (2 * D_) * 2);
    float* keysF = (float*)alloc((size_t)S_ * D_ * 4);
    float* outF = (float*)alloc((size_t)S_ * H_ * 4);
    bf16* ffn1B = (bf16*)alloc((size_t)S_ * I_ * 2);
    float* gRawF = (float*)alloc((size_t)S_ * 64 * 4);
    float* gaF = (float*)alloc((size_t)S_ * SLn * 4);
    float* gbF = (float*)alloc((size_t)S_ * SLn * 4);
    float* coefF = (float*)alloc(4200 * 4);
    float* memT = (float*)alloc((size_t)D_ * 64 * 4);
    float* pF = (float*)alloc((size_t)16 * SLn * D_ * 4);
    float* pS = (float*)alloc((size_t)16 * SLn * D_ * 4);

    coef_kernel<<<8, 256, 0, stream>>>(coefF);
    for (int l = 0; l < Lc; ++l) {
        transp(stream, W_item + (size_t)l * H_ * D_, wIQ + (size_t)l * 1536 * H_, H_, D_);
        transp(stream, W_q + (size_t)l * H_ * H_, wIQ + (size_t)l * 1536 * H_ + (size_t)512 * H_,
               H_, H_);
        transp(stream, rh_W1 + (size_t)l * D_ * 2 * D_, rh1T + (size_t)l * 2 * D_ * D_, D_, 2 * D_);
        transp(stream, rh_W2 + (size_t)l * 2 * D_ * D_, rh2T + (size_t)l * D_ * 2 * D_, 2 * D_, D_);
        transp(stream, W_out + (size_t)l * 1536 * H_, wOutT + (size_t)l * H_ * 1536, 1536, H_);
        transp(stream, ffn_W1 + (size_t)l * H_ * I_, f1T + (size_t)l * I_ * H_, H_, I_);
        transp(stream, ffn_W2 + (size_t)l * I_ * H_, f2T + (size_t)l * H_ * I_, I_, H_);
        transp(stream, gate_W + (size_t)l * 1536 * 64, gWT + (size_t)l * 64 * 1536, 1536, 64);
    }
    conv_bf16_kernel<<<(int)((size_t)V_ * H_ / 4 / 256), 256, 0, stream>>>(emb, embB);
    embed_kernel<<<S_, 256, 0, stream>>>(ids, emb, pos, hF, hB);

    for (int l = 0; l < Lc; ++l) {
        const float* fast0 = fastS + (size_t)l * SLn * D_;
        const float* slow0 = slowS + (size_t)l * SLn * D_;
        gemmM(stream, hB, 1536, wIQ + (size_t)l * 1536 * H_, b_item + l * D_, b_q + l * H_,
              itemsF, 512, qrB, 1536, itemsB, S_, 1536, H_, 33);
        gemmM(stream, itemsB, D_, rh1T + (size_t)l * 2 * D_ * D_, rh_b1 + l * 2 * D_, nullptr,
              nullptr, 0, k1B, 2 * D_, nullptr, S_, 2 * D_, D_, 11);
        gemmM(stream, k1B, 2 * D_, rh2T + (size_t)l * D_ * 2 * D_, rh_b2 + l * D_, nullptr,
              keysF, D_, nullptr, 0, nullptr, S_, D_, 2 * D_, 5);
        memt_kernel<<<128, 256, 0, stream>>>(fast0, slow0, memT);
        attn_kernel<<<S_ / 4, 256, 0, stream>>>(keysF, memT, fast0, slow0, qrB, hrB);
        gemmM(stream, hrB, 1536, gWT + (size_t)l * 64 * 1536, gate_b + l * 64, nullptr, gRawF,
              64, nullptr, 0, nullptr, S_, 64, 1536, 5);
        sigcoef_kernel<<<S_ * SLn / 256, 256, 0, stream>>>(gRawF, coefF, gaF, gbF);
        scan_part_kernel<<<256, 256, 0, stream>>>(itemsF, gaF, gbF, pF, pS);
        scan_reduce_kernel<<<64, 256, 0, stream>>>(
            pF, pS, coefF, fast0, slow0, outP + LOGITS_N + (size_t)l * SLn * D_,
            outP + LOGITS_N + (size_t)Lc * SLn * D_ + (size_t)l * SLn * D_);
        gemmM(stream, qrB, 1536, wOutT + (size_t)l * H_ * 1536, b_out + l * H_, nullptr, outF,
              H_, nullptr, 0, nullptr, S_, H_, 1536, 5);
        ln_kernel<<<S_, 256, 0, stream>>>(hF, outF, ln1_g + l * H_, ln1_b + l * H_, hF, hB, 1536);
        gemmM(stream, hB, 1536, f1T + (size_t)l * I_ * H_, ffn_b1 + l * I_, nullptr, nullptr, 0,
              ffn1B, I_, nullptr, S_, I_, H_, 11);
        gemmM(stream, ffn1B, I_, f2T + (size_t)l * H_ * I_, ffn_b2 + l * H_, nullptr, outF, H_,
              nullptr, 0, nullptr, S_, H_, I_, 5);
        ln_kernel<<<S_, 256, 0, stream>>>(hF, outF, ln2_g + l * H_, ln2_b + l * H_, hF, hB, 1536);
    }
    ln_kernel<<<S_, 256, 0, stream>>>(hF, nullptr, fln_g, fln_b, nullptr, hB, 1536);
    logits_gemm<<<1000, 512, 0, stream>>>(hB, embB, outP);
}

// Round 17
// 887.414 us; speedup vs baseline: 1.0734x; 1.0734x over previous
//
#include <hip/hip_runtime.h>
#include <hip/hip_bf16.h>
#include <stdint.h>

typedef __hip_bfloat16 bf16;
typedef float f32x4 __attribute__((ext_vector_type(4)));
typedef short s16x8 __attribute__((ext_vector_type(8)));
typedef short s16x4 __attribute__((ext_vector_type(4)));

#define DEV __device__ __forceinline__

static constexpr int S_ = 2048, H_ = 1024, D_ = 512, I_ = 4096, V_ = 32000;
static constexpr int SLn = 32, Lc = 2;
static constexpr size_t LOGITS_N = (size_t)S_ * V_;

DEV float gelu_f(float x) {
    float x3 = x * x * x;
    return 0.5f * x * (1.f + tanhf(0.7978845608028654f * (x + 0.044715f * x3)));
}

#define AS1(p) ((const __attribute__((address_space(1))) void*)(uintptr_t)(p))
#define AS3(p) ((__attribute__((address_space(3))) void*)(uint32_t)(uintptr_t)(p))

// ============ logits GEMM: 256x256, BK=32, issue-early pipelined ============
// (R10/R15 configuration — session best, verified twice: ~888us total.)
__global__ __launch_bounds__(512, 1) void logits_gemm(const bf16* __restrict__ A,
                                                      const bf16* __restrict__ BT,
                                                      float* __restrict__ C) {
    constexpr int NT = 32;
    __shared__ short lds[4 * 16384];
    const int tid = threadIdx.x, lane = tid & 63;
    const int wid = tid >> 6;
    const int wm = wid >> 2, wn = wid & 3;

    int bid = blockIdx.x;
    int wgid = (bid & 7) * 125 + (bid >> 3);
    const int m0 = (wgid & 7) * 256;
    const int n0 = (wgid >> 3) * 256;

    const int L = tid * 16;
    const int sidx = L >> 10, w = L & 1023;
    const int r16 = w >> 6;
    const int c2 = (w & 63) ^ (((r16 >> 3) & 1) << 5);
    const int srow = sidx * 16 + r16;
    const int scol = c2 >> 1;
    const bf16* aSrc[2];
    const bf16* bSrc[2];
#pragma unroll
    for (int h = 0; h < 2; ++h) {
        aSrc[h] = A + (size_t)(m0 + h * 128 + srow) * 1536 + scol;
        bSrc[h] = BT + (size_t)(n0 + h * 128 + srow) * 1024 + scol;
    }
    auto STA = [&](int kt, int h) {
        __builtin_amdgcn_global_load_lds(AS1(aSrc[h] + kt * 32),
                                         AS3(&lds[(kt & 3) * 16384 + h * 4096 + tid * 8]), 16, 0, 0);
    };
    auto STB = [&](int kt, int h) {
        __builtin_amdgcn_global_load_lds(AS1(bSrc[h] + kt * 32),
                                         AS3(&lds[(kt & 3) * 16384 + 8192 + h * 4096 + tid * 8]), 16, 0, 0);
    };

    const int laneoff = (lane & 15) * 32 + (((lane >> 4) * 8) ^ (((lane >> 3) & 1) << 4));

    f32x4 acc[8][4];
#pragma unroll
    for (int i = 0; i < 8; i++)
#pragma unroll
        for (int j = 0; j < 4; j++)
#pragma unroll
            for (int r = 0; r < 4; r++) acc[i][j][r] = 0.f;

    s16x8 a0[4], a1[4], b0[4], b1[4];
    auto rdA = [&](s16x8(&d)[4], int kt, int mq) {
        const short* p = &lds[(kt & 3) * 16384 + wm * 4096 + mq * 2048];
#pragma unroll
        for (int f = 0; f < 4; ++f) d[f] = *(const s16x8*)&p[f * 512 + laneoff];
    };
    auto rdB = [&](s16x8(&d)[4], int kt) {
        const short* p = &lds[(kt & 3) * 16384 + 8192 + wn * 2048];
#pragma unroll
        for (int j = 0; j < 4; ++j) d[j] = *(const s16x8*)&p[j * 512 + laneoff];
    };
    auto MM = [&](int mq, s16x8(&a)[4], s16x8(&b)[4]) {
        __builtin_amdgcn_s_setprio(1);
#pragma unroll
        for (int f = 0; f < 4; ++f)
#pragma unroll
            for (int j = 0; j < 4; ++j)
                acc[mq * 4 + f][j] =
                    __builtin_amdgcn_mfma_f32_16x16x32_bf16(a[f], b[j], acc[mq * 4 + f][j], 0, 0, 0);
        __builtin_amdgcn_s_setprio(0);
    };

#define GATE(tight)                                                     \
    do {                                                                \
        __builtin_amdgcn_s_barrier();                                   \
        if (tight) asm volatile("s_waitcnt vmcnt(0)" ::: "memory");     \
        else       asm volatile("s_waitcnt vmcnt(4)" ::: "memory");     \
        asm volatile("s_waitcnt lgkmcnt(0)" ::: "memory");              \
        __builtin_amdgcn_sched_barrier(0);                              \
    } while (0)
#define SB() __builtin_amdgcn_sched_barrier(0)

#pragma unroll
    for (int kt = 0; kt < 3; ++kt) {
        STA(kt, 0); STA(kt, 1); STB(kt, 0); STB(kt, 1);
    }
    asm volatile("s_waitcnt vmcnt(4)" ::: "memory");
    __builtin_amdgcn_s_barrier();
    rdA(a0, 0, 0);
    rdB(b0, 0);

    for (int tt = 0; tt < NT; tt += 2) {
        {
            const int t = tt;
            const bool tight = (t >= NT - 2);
            GATE(tight);
            rdA(a1, t, 1);
            SB();
            MM(0, a0, b0);
            if (t + 3 < NT) { STA(t + 3, 0); STA(t + 3, 1); }
            GATE(tight);
            if (t + 1 < NT) { rdA(a0, t + 1, 0); rdB(b1, t + 1); }
            SB();
            MM(1, a1, b0);
            if (t + 3 < NT) { STB(t + 3, 0); STB(t + 3, 1); }
        }
        {
            const int t = tt + 1;
            const bool tight = (t >= NT - 2);
            GATE(tight);
            rdA(a1, t, 1);
            SB();
            MM(0, a0, b1);
            if (t + 3 < NT) { STA(t + 3, 0); STA(t + 3, 1); }
            GATE(tight);
            if (t + 1 < NT) { rdA(a0, t + 1, 0); rdB(b0, t + 1); }
            SB();
            MM(1, a1, b1);
            if (t + 3 < NT) { STB(t + 3, 0); STB(t + 3, 1); }
        }
    }
#undef GATE
#undef SB

#pragma unroll
    for (int i = 0; i < 8; i++) {
        int gr0 = m0 + wm * 128 + i * 16 + ((lane >> 4) << 2);
#pragma unroll
        for (int j = 0; j < 4; j++) {
            int gc = n0 + wn * 64 + j * 16 + (lane & 15);
#pragma unroll
            for (int r = 0; r < 4; r++) C[(size_t)(gr0 + r) * V_ + gc] = acc[i][j][r];
        }
    }
}

// ======================= unified pipelined GEMM (NT) ========================
// BK=32, 4 LDS slots, 3-ahead prefetch, R8-fixed vmcnt ladder (passed 7x).
// FLAGS: 1=bias, 2=gelu, 4=f32, 8=bf16, 32=IQ-route
template <int BM, int BN, int TH, int WM, int WN, int FLAGS>
__global__ __launch_bounds__(TH, 3) void gemm_p5(
    const bf16* __restrict__ A, int lda, const bf16* __restrict__ BT,
    const float* __restrict__ bias, const float* __restrict__ bias2,
    float* __restrict__ Cf, int ldf, bf16* __restrict__ Cb, int ldb2,
    bf16* __restrict__ Cb2, int K, int Mt, int Nt) {
    constexpr int FM = BM / (WM * 16), FN = BN / (WN * 16);
    constexpr int CA = (BM * 4) / TH, CB = (BN * 4) / TH, CH = CA + CB;
    constexpr int NPH = (FM * FN >= 32) ? 2 : 1;
    constexpr int FMP = FM / NPH;
    constexpr int BUFS = (BM + BN) * 32;
    __shared__ short lds[4 * BUFS];
    const int tid = threadIdx.x, lane = tid & 63;
    const int wm = (tid >> 6) / WN, wn = (tid >> 6) % WN;

    int nwg = Mt * Nt;
    int bid = blockIdx.x, wgid = bid;
    if ((nwg & 7) == 0) {
        int cpx = nwg >> 3;
        wgid = (bid & 7) * cpx + (bid >> 3);
    }
    const int m0 = (wgid % Mt) * BM, n0 = (wgid / Mt) * BN;

    const bf16* aS[CA];
    const bf16* bS[CB];
#pragma unroll
    for (int c = 0; c < CA; ++c) {
        int L = (c * TH + tid) * 16;
        int sidx = L >> 10, w = L & 1023;
        int r16 = w >> 6;
        int c2 = (w & 63) ^ (((r16 >> 3) & 1) << 5);
        aS[c] = A + (size_t)(m0 + sidx * 16 + r16) * lda + (c2 >> 1);
    }
#pragma unroll
    for (int c = 0; c < CB; ++c) {
        int L = (c * TH + tid) * 16;
        int sidx = L >> 10, w = L & 1023;
        int r16 = w >> 6;
        int c2 = (w & 63) ^ (((r16 >> 3) & 1) << 5);
        bS[c] = BT + (size_t)(n0 + sidx * 16 + r16) * K + (c2 >> 1);
    }

    auto stageA = [&](int kt) {
        short* dst = &lds[(kt & 3) * BUFS];
#pragma unroll
        for (int c = 0; c < CA; ++c)
            __builtin_amdgcn_global_load_lds(AS1(aS[c] + kt * 32), AS3(dst + (c * TH + tid) * 8), 16, 0, 0);
    };
    auto stageB = [&](int kt) {
        short* dst = &lds[(kt & 3) * BUFS + BM * 32];
#pragma unroll
        for (int c = 0; c < CB; ++c)
            __builtin_amdgcn_global_load_lds(AS1(bS[c] + kt * 32), AS3(dst + (c * TH + tid) * 8), 16, 0, 0);
    };

    const int laneoff = ((lane & 15) * 64 + ((((lane >> 4) * 8) ^ (((lane >> 3) & 1) << 4)) << 1)) >> 1;

    f32x4 acc[FM][FN];
#pragma unroll
    for (int i = 0; i < FM; i++)
#pragma unroll
        for (int j = 0; j < FN; j++)
#pragma unroll
            for (int r = 0; r < 4; r++) acc[i][j][r] = 0.f;

    const int NT = K >> 5;
    stageA(0); stageB(0);
    stageA(1); stageB(1);
    stageA(2); stageB(2);
    asm volatile("s_waitcnt vmcnt(%0)" ::"n"(2 * CH) : "memory");
    __builtin_amdgcn_s_barrier();
    for (int t = 0; t < NT; ++t) {
        const short* as = &lds[(t & 3) * BUFS];
        const short* bs = as + BM * 32;
        s16x8 bf[FN];
#pragma unroll
        for (int p = 0; p < NPH; ++p) {
            s16x8 af[FMP];
#pragma unroll
            for (int i = 0; i < FMP; i++)
                af[i] = *(const s16x8*)&as[(wm * FM + p * FMP + i) * 512 + laneoff];
            if (p == 0) {
#pragma unroll
                for (int j = 0; j < FN; j++)
                    bf[j] = *(const s16x8*)&bs[(wn * FN + j) * 512 + laneoff];
            }
            if (t + 3 < NT) {
                if (NPH == 1) {
                    stageA(t + 3);
                    stageB(t + 3);
                } else if (p == 0) {
                    stageA(t + 3);
                } else {
                    stageB(t + 3);
                }
            }
            if (p == NPH - 1) {
                const int rem = NT - 1 - t;
                if (rem >= 3)
                    asm volatile("s_waitcnt vmcnt(%0)" ::"n"(2 * CH) : "memory");
                else if (rem == 2)
                    asm volatile("s_waitcnt vmcnt(%0)" ::"n"(CH) : "memory");
                else
                    asm volatile("s_waitcnt vmcnt(0)" ::: "memory");
            }
            __builtin_amdgcn_s_barrier();
            __builtin_amdgcn_sched_barrier(0);
            __builtin_amdgcn_s_setprio(1);
#pragma unroll
            for (int i = 0; i < FMP; i++)
#pragma unroll
                for (int j = 0; j < FN; j++)
                    acc[p * FMP + i][j] =
                        __builtin_amdgcn_mfma_f32_16x16x32_bf16(af[i], bf[j], acc[p * FMP + i][j], 0, 0, 0);
            __builtin_amdgcn_s_setprio(0);
            __builtin_amdgcn_s_barrier();
        }
    }

#pragma unroll
    for (int i = 0; i < FM; i++) {
        int gr0 = m0 + (wm * FM + i) * 16 + ((lane >> 4) << 2);
#pragma unroll
        for (int j = 0; j < FN; j++) {
            int gc = n0 + (wn * FN + j) * 16 + (lane & 15);
            if (FLAGS & 32) {
                if (gc < 512) {
                    float bv = bias[gc];
#pragma unroll
                    for (int r = 0; r < 4; r++) {
                        float v = acc[i][j][r] + bv;
                        Cf[(size_t)(gr0 + r) * 512 + gc] = v;
                        Cb2[(size_t)(gr0 + r) * 512 + gc] = __float2bfloat16(v);
                    }
                } else {
                    float bv = bias2[gc - 512];
#pragma unroll
                    for (int r = 0; r < 4; r++)
                        Cb[(size_t)(gr0 + r) * 1536 + (gc - 512)] = __float2bfloat16(acc[i][j][r] + bv);
                }
            } else {
                float bv = (FLAGS & 1) ? bias[gc] : 0.f;
#pragma unroll
                for (int r = 0; r < 4; r++) {
                    float v = acc[i][j][r] + bv;
                    if (FLAGS & 2) v = gelu_f(v);
                    if (FLAGS & 4) Cf[(size_t)(gr0 + r) * ldf + gc] = v;
                    if (FLAGS & 8) Cb[(size_t)(gr0 + r) * ldb2 + gc] = __float2bfloat16(v);
                }
            }
        }
    }
}

// ------------------------ transpose f32 -> bf16^T ---------------------------
__global__ __launch_bounds__(256) void transpose_bf16_kernel(const float* __restrict__ W,
                                                             bf16* __restrict__ WT, int K, int N) {
    __shared__ float t[32][33];
    int tx = threadIdx.x & 31, ty = threadIdx.x >> 5;
    int kb = blockIdx.y * 32, nb = blockIdx.x * 32;
#pragma unroll
    for (int i = 0; i < 4; i++)
        t[ty + 8 * i][tx] = W[(size_t)(kb + ty + 8 * i) * N + nb + tx];
    __syncthreads();
#pragma unroll
    for (int i = 0; i < 4; i++)
        WT[(size_t)(nb + ty + 8 * i) * K + kb + tx] = __float2bfloat16(t[tx][ty + 8 * i]);
}

// ------------------------------ f32 -> bf16 ---------------------------------
__global__ void conv_bf16_kernel(const float* __restrict__ src, bf16* __restrict__ dst) {
    size_t i = (size_t)blockIdx.x * 256 + threadIdx.x;
    f32x4 v = ((const f32x4*)src)[i];
    s16x4 o;
#pragma unroll
    for (int j = 0; j < 4; j++) {
        bf16 h = __float2bfloat16(v[j]);
        o[j] = *(short*)&h;
    }
    ((s16x4*)dst)[i] = o;
}

// ------------------------------ embedding ----------------------------------
__global__ void embed_kernel(const int* __restrict__ ids, const float* __restrict__ emb,
                             const float* __restrict__ pos, float* __restrict__ hF,
                             bf16* __restrict__ hB) {
    int t = blockIdx.x, tid = threadIdx.x;
    int id = ids[t];
    f32x4 v = ((const f32x4*)(emb + (size_t)id * H_))[tid];
    f32x4 q = ((const f32x4*)(pos + (size_t)t * H_))[tid];
    v = v + q;
    ((f32x4*)(hF + (size_t)t * H_))[tid] = v;
    s16x4 o;
#pragma unroll
    for (int j = 0; j < 4; j++) {
        bf16 h = __float2bfloat16(v[j]);
        o[j] = *(short*)&h;
    }
    ((s16x4*)(hB + (size_t)t * 1536))[tid] = o;
}

// ------------------------------ LayerNorm ----------------------------------
__global__ __launch_bounds__(256) void ln_kernel(const float* __restrict__ x,
                                                 const float* __restrict__ res,
                                                 const float* __restrict__ g,
                                                 const float* __restrict__ b,
                                                 float* __restrict__ of, bf16* __restrict__ ob,
                                                 int ldo) {
    __shared__ float red[8];
    int row = blockIdx.x, tid = threadIdx.x, lane = tid & 63, wid = tid >> 6;
    const float* xr = x + (size_t)row * H_;
    float v[4];
#pragma unroll
    for (int j = 0; j < 4; j++) {
        int c = tid + 256 * j;
        v[j] = xr[c] + (res ? res[(size_t)row * H_ + c] : 0.f);
    }
    float s = v[0] + v[1] + v[2] + v[3];
#pragma unroll
    for (int o = 32; o; o >>= 1) s += __shfl_xor(s, o);
    if (!lane) red[wid] = s;
    __syncthreads();
    float mean = (red[0] + red[1] + red[2] + red[3]) * (1.f / H_);
    float q = 0.f;
#pragma unroll
    for (int j = 0; j < 4; j++) {
        float d = v[j] - mean;
        q += d * d;
    }
#pragma unroll
    for (int o = 32; o; o >>= 1) q += __shfl_xor(q, o);
    if (!lane) red[4 + wid] = q;
    __syncthreads();
    float var = (red[4] + red[5] + red[6] + red[7]) * (1.f / H_);
    float rstd = rsqrtf(var + 1e-5f);
#pragma unroll
    for (int j = 0; j < 4; j++) {
        int c = tid + 256 * j;
        float o2 = (v[j] - mean) * rstd * g[c] + b[c];
        if (of) of[(size_t)row * H_ + c] = o2;
        if (ob) ob[(size_t)row * ldo + c] = __float2bfloat16(o2);
    }
}

// --------------------- mem transpose for attn scores ------------------------
__global__ void memt_kernel(const float* __restrict__ fast0, const float* __restrict__ slow0,
                            float* __restrict__ memT) {
    int idx = blockIdx.x * 256 + threadIdx.x;
    int d = idx >> 6, n = idx & 63;
    const float* m = (n < 32) ? fast0 + (size_t)n * D_ : slow0 + (size_t)(n - 32) * D_;
    memT[idx] = m[d];
}

// ---------------- attention (fused keynorm), 1 q-row per wave ---------------
__global__ __launch_bounds__(256) void attn_kernel(const float* __restrict__ keys,
                                                   const float* __restrict__ memT,
                                                   const float* __restrict__ fast0,
                                                   const float* __restrict__ slow0,
                                                   bf16* __restrict__ qr, bf16* __restrict__ hr) {
    __shared__ float klds[4][512];
    int wid = threadIdx.x >> 6, lane = threadIdx.x & 63;
    int r = blockIdx.x * 4 + wid;
    float kv[8], ss = 0.f;
#pragma unroll
    for (int j = 0; j < 8; j++) {
        kv[j] = keys[(size_t)r * D_ + lane + 64 * j];
        ss += kv[j] * kv[j];
    }
#pragma unroll
    for (int o = 32; o; o >>= 1) ss += __shfl_xor(ss, o);
    float inv = 1.f / (sqrtf(ss) + 1e-6f);
#pragma unroll
    for (int j = 0; j < 8; j++) {
        kv[j] *= inv;
        klds[wid][lane + 64 * j] = kv[j];
    }
    __syncthreads();
    float s0 = 0.f, s1 = 0.f, s2 = 0.f, s3 = 0.f;
#pragma unroll 8
    for (int d = 0; d < 512; d += 4) {
        s0 = fmaf(klds[wid][d + 0], memT[(d + 0) * 64 + lane], s0);
        s1 = fmaf(klds[wid][d + 1], memT[(d + 1) * 64 + lane], s1);
        s2 = fmaf(klds[wid][d + 2], memT[(d + 2) * 64 + lane], s2);
        s3 = fmaf(klds[wid][d + 3], memT[(d + 3) * 64 + lane], s3);
    }
    float s = (s0 + s1 + s2 + s3) * 0.044194173824159216f;
    float m = s;
#pragma unroll
    for (int o = 32; o; o >>= 1) m = fmaxf(m, __shfl_xor(m, o));
    float p = expf(s - m);
    float sum = p;
#pragma unroll
    for (int o = 32; o; o >>= 1) sum += __shfl_xor(sum, o);
    float pn = p / sum;
    float rv[8];
#pragma unroll
    for (int j = 0; j < 8; j++) rv[j] = 0.f;
    for (int n2 = 0; n2 < 64; ++n2) {
        float a2 = __shfl(pn, n2);
        const float* m2 = (n2 < 32) ? (fast0 + (size_t)n2 * D_) : (slow0 + (size_t)(n2 - 32) * D_);
#pragma unroll
        for (int j = 0; j < 8; j++) rv[j] = fmaf(a2, m2[lane + 64 * j], rv[j]);
    }
#pragma unroll
    for (int j = 0; j < 8; j++) {
        bf16 o = __float2bfloat16(rv[j] * kv[j]);
        qr[(size_t)r * 1536 + 1024 + lane + 64 * j] = o;
        hr[(size_t)r * 1536 + 1024 + lane + 64 * j] = o;
    }
}

// ------------------------- scan coefficients --------------------------------
__global__ void coef_kernel(float* __restrict__ coef) {
    int t = blockIdx.x * 256 + threadIdx.x;
    int j0 = (t + 9) / 10;
    float a = powf(0.9f, (float)(2047 - t + 205 - j0));
    float b = 0.f;
    for (int j = j0; j < 205; ++j)
        b += powf(0.9f, (float)(10 * j - t + j - j0)) * powf(0.99f, (float)(204 - j));
    b *= 0.1f;
    coef[t] = a;
    coef[2048 + t] = b;
    if (t == 0) {
        coef[4096] = powf(0.99f, 205.f);
        float cfs = 0.f;
        for (int j = 0; j < 205; ++j)
            cfs += powf(0.9f, (float)(11 * j + 1)) * powf(0.99f, (float)(204 - j));
        coef[4097] = 0.1f * cfs;
    }
}

// -------------------- gates epilogue: sigmoid * coef ------------------------
__global__ void sigcoef_kernel(const float* __restrict__ raw, const float* __restrict__ coef,
                               float* __restrict__ ga, float* __restrict__ gb) {
    int i = blockIdx.x * 256 + threadIdx.x;
    int r = i >> 5, n = i & 31;
    float g = 1.f / (1.f + expf(-raw[r * 64 + n]));
    ga[i] = g * coef[r];
    gb[i] = g * coef[2048 + r];
}

// ------------------------- scan: split-T partial GEMMs ----------------------
__global__ __launch_bounds__(256) void scan_part_kernel(const float* __restrict__ items,
                                                        const float* __restrict__ ga,
                                                        const float* __restrict__ gb,
                                                        float* __restrict__ pF,
                                                        float* __restrict__ pS) {
    int tid = threadIdx.x;
    int d = (blockIdx.x & 7) * 64 + (tid & 63);
    int mg = (blockIdx.x >> 3) & 1;
    int tc = blockIdx.x >> 4;
    int m0 = mg * 16 + (tid >> 6) * 4;
    float aF[4] = {0.f, 0.f, 0.f, 0.f}, aS[4] = {0.f, 0.f, 0.f, 0.f};
    for (int t = tc * 128; t < tc * 128 + 128; ++t) {
        float it = items[(size_t)t * D_ + d];
#pragma unroll
        for (int j = 0; j < 4; j++) {
            aF[j] = fmaf(ga[t * 32 + m0 + j], it, aF[j]);
            aS[j] = fmaf(gb[t * 32 + m0 + j], it, aS[j]);
        }
    }
#pragma unroll
    for (int j = 0; j < 4; j++) {
        pF[((size_t)tc * 32 + m0 + j) * D_ + d] = aF[j];
        pS[((size_t)tc * 32 + m0 + j) * D_ + d] = aS[j];
    }
}

__global__ __launch_bounds__(256) void scan_reduce_kernel(const float* __restrict__ pF,
                                                          const float* __restrict__ pS,
                                                          const float* __restrict__ coef,
                                                          const float* __restrict__ fast0,
                                                          const float* __restrict__ slow0,
                                                          float* __restrict__ fastO,
                                                          float* __restrict__ slowO) {
    int i = blockIdx.x * 256 + threadIdx.x;
    float f = 0.f, s = 0.f;
#pragma unroll
    for (int c = 0; c < 16; c++) {
        f += pF[(size_t)c * 32 * D_ + i];
        s += pS[(size_t)c * 32 * D_ + i];
    }
    fastO[i] = f;
    slowO[i] = s + coef[4096] * slow0[i] + coef[4097] * fast0[i];
}

// ------------------------------- host side ----------------------------------
static inline void gemmM(hipStream_t st, const bf16* A, int lda, const bf16* BT,
                         const float* bias, const float* bias2, float* Cf, int ldf, bf16* Cb,
                         int ldb2, bf16* Cb2, int M, int N, int K, int flags) {
    if (N >= 1536 && (N % 128) == 0) {
        int Mt = M / 128, Nt = N / 128;
        dim3 g(Mt * Nt), b(256);
        if (flags == 33)
            gemm_p5<128, 128, 256, 2, 2, 33><<<g, b, 0, st>>>(A, lda, BT, bias, bias2, Cf, ldf,
                                                              Cb, ldb2, Cb2, K, Mt, Nt);
        else if (flags == 11)
            gemm_p5<128, 128, 256, 2, 2, 11><<<g, b, 0, st>>>(A, lda, BT, bias, bias2, Cf, ldf,
                                                              Cb, ldb2, Cb2, K, Mt, Nt);
        else
            gemm_p5<128, 128, 256, 2, 2, 5><<<g, b, 0, st>>>(A, lda, BT, bias, bias2, Cf, ldf,
                                                             Cb, ldb2, Cb2, K, Mt, Nt);
        return;
    }
    int Mt = M / 128, Nt = N / 64;
    dim3 g(Mt * Nt), b(256);
    if (flags == 11)
        gemm_p5<128, 64, 256, 2, 2, 11><<<g, b, 0, st>>>(A, lda, BT, bias, bias2, Cf, ldf, Cb,
                                                         ldb2, Cb2, K, Mt, Nt);
    else
        gemm_p5<128, 64, 256, 2, 2, 5><<<g, b, 0, st>>>(A, lda, BT, bias, bias2, Cf, ldf, Cb,
                                                        ldb2, Cb2, K, Mt, Nt);
}

static inline void transp(hipStream_t st, const float* W, bf16* WT, int K, int N) {
    transpose_bf16_kernel<<<dim3(N / 32, K / 32), 256, 0, st>>>(W, WT, K, N);
}

extern "C" void kernel_launch(void* const* d_in, const int* in_sizes, int n_in,
                              void* d_out, int out_size, void* d_ws, size_t ws_size,
                              hipStream_t stream) {
    const int* ids = (const int*)d_in[0];
    const float* fastS = (const float*)d_in[1];
    const float* slowS = (const float*)d_in[2];
    const float* emb = (const float*)d_in[3];
    const float* pos = (const float*)d_in[4];
    const float* W_item = (const float*)d_in[5];
    const float* b_item = (const float*)d_in[6];
    const float* W_q = (const float*)d_in[7];
    const float* b_q = (const float*)d_in[8];
    const float* rh_W1 = (const float*)d_in[9];
    const float* rh_b1 = (const float*)d_in[10];
    const float* rh_W2 = (const float*)d_in[11];
    const float* rh_b2 = (const float*)d_in[12];
    const float* gate_W = (const float*)d_in[13];
    const float* gate_b = (const float*)d_in[14];
    const float* W_out = (const float*)d_in[15];
    const float* b_out = (const float*)d_in[16];
    const float* ln1_g = (const float*)d_in[17];
    const float* ln1_b = (const float*)d_in[18];
    const float* ffn_W1 = (const float*)d_in[19];
    const float* ffn_b1 = (const float*)d_in[20];
    const float* ffn_W2 = (const float*)d_in[21];
    const float* ffn_b2 = (const float*)d_in[22];
    const float* ln2_g = (const float*)d_in[23];
    const float* ln2_b = (const float*)d_in[24];
    const float* fln_g = (const float*)d_in[25];
    const float* fln_b = (const float*)d_in[26];
    float* outP = (float*)d_out;

    size_t off = 0;
    char* base = (char*)d_ws;
    auto alloc = [&](size_t n) -> char* {
        char* p = base + off;
        off += (n + 255) & ~(size_t)255;
        return p;
    };
    bf16* wIQ = (bf16*)alloc((size_t)Lc * 1536 * H_ * 2);
    bf16* rh1T = (bf16*)alloc((size_t)Lc * (2 * D_) * D_ * 2);
    bf16* rh2T = (bf16*)alloc((size_t)Lc * D_ * (2 * D_) * 2);
    bf16* wOutT = (bf16*)alloc((size_t)Lc * H_ * 1536 * 2);
    bf16* f1T = (bf16*)alloc((size_t)Lc * I_ * H_ * 2);
    bf16* f2T = (bf16*)alloc((size_t)Lc * H_ * I_ * 2);
    bf16* gWT = (bf16*)alloc((size_t)Lc * 64 * 1536 * 2);
    bf16* embB = (bf16*)alloc((size_t)V_ * H_ * 2);
    float* hF = (float*)alloc((size_t)S_ * H_ * 4);
    bf16* hrB = (bf16*)alloc((size_t)S_ * 1536 * 2);
    bf16* hB = hrB;
    float* itemsF = (float*)alloc((size_t)S_ * D_ * 4);
    bf16* itemsB = (bf16*)alloc((size_t)S_ * D_ * 2);
    bf16* qrB = (bf16*)alloc((size_t)S_ * 1536 * 2);
    bf16* k1B = (bf16*)alloc((size_t)S_ * (2 * D_) * 2);
    float* keysF = (float*)alloc((size_t)S_ * D_ * 4);
    float* outF = (float*)alloc((size_t)S_ * H_ * 4);
    bf16* ffn1B = (bf16*)alloc((size_t)S_ * I_ * 2);
    float* gRawF = (float*)alloc((size_t)S_ * 64 * 4);
    float* gaF = (float*)alloc((size_t)S_ * SLn * 4);
    float* gbF = (float*)alloc((size_t)S_ * SLn * 4);
    float* coefF = (float*)alloc(4200 * 4);
    float* memT = (float*)alloc((size_t)D_ * 64 * 4);
    float* pF = (float*)alloc((size_t)16 * SLn * D_ * 4);
    float* pS = (float*)alloc((size_t)16 * SLn * D_ * 4);

    coef_kernel<<<8, 256, 0, stream>>>(coefF);
    for (int l = 0; l < Lc; ++l) {
        transp(stream, W_item + (size_t)l * H_ * D_, wIQ + (size_t)l * 1536 * H_, H_, D_);
        transp(stream, W_q + (size_t)l * H_ * H_, wIQ + (size_t)l * 1536 * H_ + (size_t)512 * H_,
               H_, H_);
        transp(stream, rh_W1 + (size_t)l * D_ * 2 * D_, rh1T + (size_t)l * 2 * D_ * D_, D_, 2 * D_);
        transp(stream, rh_W2 + (size_t)l * 2 * D_ * D_, rh2T + (size_t)l * D_ * 2 * D_, 2 * D_, D_);
        transp(stream, W_out + (size_t)l * 1536 * H_, wOutT + (size_t)l * H_ * 1536, 1536, H_);
        transp(stream, ffn_W1 + (size_t)l * H_ * I_, f1T + (size_t)l * I_ * H_, H_, I_);
        transp(stream, ffn_W2 + (size_t)l * I_ * H_, f2T + (size_t)l * H_ * I_, I_, H_);
        transp(stream, gate_W + (size_t)l * 1536 * 64, gWT + (size_t)l * 64 * 1536, 1536, 64);
    }
    conv_bf16_kernel<<<(int)((size_t)V_ * H_ / 4 / 256), 256, 0, stream>>>(emb, embB);
    embed_kernel<<<S_, 256, 0, stream>>>(ids, emb, pos, hF, hB);

    for (int l = 0; l < Lc; ++l) {
        const float* fast0 = fastS + (size_t)l * SLn * D_;
        const float* slow0 = slowS + (size_t)l * SLn * D_;
        gemmM(stream, hB, 1536, wIQ + (size_t)l * 1536 * H_, b_item + l * D_, b_q + l * H_,
              itemsF, 512, qrB, 1536, itemsB, S_, 1536, H_, 33);
        gemmM(stream, itemsB, D_, rh1T + (size_t)l * 2 * D_ * D_, rh_b1 + l * 2 * D_, nullptr,
              nullptr, 0, k1B, 2 * D_, nullptr, S_, 2 * D_, D_, 11);
        gemmM(stream, k1B, 2 * D_, rh2T + (size_t)l * D_ * 2 * D_, rh_b2 + l * D_, nullptr,
              keysF, D_, nullptr, 0, nullptr, S_, D_, 2 * D_, 5);
        memt_kernel<<<128, 256, 0, stream>>>(fast0, slow0, memT);
        attn_kernel<<<S_ / 4, 256, 0, stream>>>(keysF, memT, fast0, slow0, qrB, hrB);
        gemmM(stream, hrB, 1536, gWT + (size_t)l * 64 * 1536, gate_b + l * 64, nullptr, gRawF,
              64, nullptr, 0, nullptr, S_, 64, 1536, 5);
        sigcoef_kernel<<<S_ * SLn / 256, 256, 0, stream>>>(gRawF, coefF, gaF, gbF);
        scan_part_kernel<<<256, 256, 0, stream>>>(itemsF, gaF, gbF, pF, pS);
        scan_reduce_kernel<<<64, 256, 0, stream>>>(
            pF, pS, coefF, fast0, slow0, outP + LOGITS_N + (size_t)l * SLn * D_,
            outP + LOGITS_N + (size_t)Lc * SLn * D_ + (size_t)l * SLn * D_);
        gemmM(stream, qrB, 1536, wOutT + (size_t)l * H_ * 1536, b_out + l * H_, nullptr, outF,
              H_, nullptr, 0, nullptr, S_, H_, 1536, 5);
        ln_kernel<<<S_, 256, 0, stream>>>(hF, outF, ln1_g + l * H_, ln1_b + l * H_, hF, hB, 1536);
        gemmM(stream, hB, 1536, f1T + (size_t)l * I_ * H_, ffn_b1 + l * I_, nullptr, nullptr, 0,
              ffn1B, I_, nullptr, S_, I_, H_, 11);
        gemmM(stream, ffn1B, I_, f2T + (size_t)l * H_ * I_, ffn_b2 + l * H_, nullptr, outF, H_,
              nullptr, 0, nullptr, S_, H_, I_, 5);
        ln_kernel<<<S_, 256, 0, stream>>>(hF, outF, ln2_g + l * H_, ln2_b + l * H_, hF, hB, 1536);
    }
    ln_kernel<<<S_, 256, 0, stream>>>(hF, nullptr, fln_g, fln_b, nullptr, hB, 1536);
    logits_gemm<<<1000, 512, 0, stream>>>(hB, embB, outP);
}